// Round 1
// baseline (1194.137 us; speedup 1.0000x reference)
//
#include <hip/hip_runtime.h>
#include <hip/hip_bf16.h>

// Model dims
#define LNUM 2
#define BATCH 4
#define DMODEL 2048
#define NH 16
#define NKV 8
#define HDIM 128
#define FDIM 8192
#define VOCAB 32000
#define MAXP 4096
#define EPSV 1e-6f

// ---------------- embed ----------------
__global__ __launch_bounds__(256) void embed_kernel(
    const float* __restrict__ embw, const int* __restrict__ tok, float* __restrict__ x)
{
    int b = blockIdx.x;
    int t = tok[b];
    const float* src = embw + (size_t)t * DMODEL;
    for (int d = threadIdx.x; d < DMODEL; d += 256)
        x[b * DMODEL + d] = src[d];
}

// ---------------- rmsnorm rows ----------------
__global__ __launch_bounds__(256) void rmsnorm_rows(
    const float* __restrict__ in, const float* __restrict__ w, float* __restrict__ out, int D)
{
    int r = blockIdx.x;
    const float* x = in + (size_t)r * D;
    float s = 0.f;
    for (int d = threadIdx.x; d < D; d += 256) { float v = x[d]; s += v * v; }
    __shared__ float red[4];
    #pragma unroll
    for (int off = 32; off; off >>= 1) s += __shfl_xor(s, off);
    int wave = threadIdx.x >> 6, lane = threadIdx.x & 63;
    if (lane == 0) red[wave] = s;
    __syncthreads();
    float tot = red[0] + red[1] + red[2] + red[3];
    float rr = rsqrtf(tot / (float)D + EPSV);
    for (int d = threadIdx.x; d < D; d += 256)
        out[(size_t)r * D + d] = x[d] * rr * w[d];
}

// ---------------- generic GEMV tile core ----------------
// act staged in LDS as [d][4] (float4 per d). Each thread: VEC consecutive cols,
// its wave's BD/4 d-slice. atomicAdd epilogue (split-D partials).
template<int VEC, int BD>
__device__ __forceinline__ void gemv_tile(
    const float* __restrict__ Wblk,   // &W[d0*O + colBlockBase]
    size_t O,
    const float* __restrict__ actLds, // [BD][4]
    float* __restrict__ outBlk,       // &out[colBlockBase]
    size_t outO)
{
    int t = threadIdx.x;
    int lane = t & 63, wave = t >> 6;
    constexpr int WD = BD / 4;
    int dloc = wave * WD;
    int c = lane * VEC;
    float acc[BATCH][VEC];
    #pragma unroll
    for (int b = 0; b < BATCH; ++b)
        #pragma unroll
        for (int j = 0; j < VEC; ++j) acc[b][j] = 0.f;

    const float* wp = Wblk + (size_t)dloc * O + c;
    #pragma unroll 8
    for (int i = 0; i < WD; ++i) {
        float wv[VEC];
        if constexpr (VEC == 4) {
            float4 f = *(const float4*)wp;
            wv[0] = f.x; wv[1] = f.y; wv[2] = f.z; wv[3] = f.w;
        } else {
            float2 f = *(const float2*)wp;
            wv[0] = f.x; wv[1] = f.y;
        }
        wp += O;
        float4 a4 = *(const float4*)&actLds[(dloc + i) * 4];
        float av[4] = {a4.x, a4.y, a4.z, a4.w};
        #pragma unroll
        for (int b = 0; b < BATCH; ++b)
            #pragma unroll
            for (int j = 0; j < VEC; ++j)
                acc[b][j] = fmaf(av[b], wv[j], acc[b][j]);
    }
    #pragma unroll
    for (int b = 0; b < BATCH; ++b)
        #pragma unroll
        for (int j = 0; j < VEC; ++j)
            atomicAdd(&outBlk[(size_t)b * outO + c + j], acc[b][j]);
}

template<int BD>
__device__ __forceinline__ void stage_act(
    const float* __restrict__ act, int D, int d0, float* __restrict__ lds)
{
    for (int i = threadIdx.x; i < 4 * BD; i += 256) {
        int dd = i >> 2, b = i & 3;
        lds[i] = act[(size_t)b * D + d0 + dd];
    }
    __syncthreads();
}

// plain gemv: out[b,o] += sum_d act[b,d] * W[d,o]
template<int VEC, int BD>
__global__ __launch_bounds__(256) void gemv_plain(
    const float* __restrict__ W, const float* __restrict__ act,
    float* __restrict__ out, int D, int O)
{
    __shared__ float lds[4 * BD];
    int d0 = blockIdx.y * BD;
    int cb = blockIdx.x * (64 * VEC);
    stage_act<BD>(act, D, d0, lds);
    gemv_tile<VEC, BD>(W + (size_t)d0 * O + cb, O, lds, out + cb, O);
}

// fused QKV: col space [0,4096): wq cols 0..2047, wk 2048..3071, wv 3072..4095
__global__ __launch_bounds__(256) void gemv_qkv(
    const float* __restrict__ wq, const float* __restrict__ wk, const float* __restrict__ wv,
    const float* __restrict__ act, float* __restrict__ q, float* __restrict__ k, float* __restrict__ v)
{
    constexpr int VEC = 2, BD = 256;
    __shared__ float lds[4 * BD];
    int d0 = blockIdx.y * BD;
    int cb = blockIdx.x * (64 * VEC);   // 128-wide tiles
    stage_act<BD>(act, DMODEL, d0, lds);
    const float* W; float* out; size_t O; int c;
    if (cb < 2048)      { W = wq; out = q; O = 2048; c = cb; }
    else if (cb < 3072) { W = wk; out = k; O = 1024; c = cb - 2048; }
    else                { W = wv; out = v; O = 1024; c = cb - 3072; }
    gemv_tile<VEC, BD>(W + (size_t)d0 * O + c, O, lds, out + c, O);
}

// fused gate+up: col space [0,16384)
__global__ __launch_bounds__(256) void gemv_gateup(
    const float* __restrict__ wg, const float* __restrict__ wu,
    const float* __restrict__ act, float* __restrict__ g, float* __restrict__ u)
{
    constexpr int VEC = 4, BD = 256;
    __shared__ float lds[4 * BD];
    int d0 = blockIdx.y * BD;
    int cb = blockIdx.x * (64 * VEC);   // 256-wide tiles
    stage_act<BD>(act, DMODEL, d0, lds);
    const float* W = (cb < FDIM) ? wg : wu;
    float* out = (cb < FDIM) ? g : u;
    int c = (cb < FDIM) ? cb : cb - FDIM;
    gemv_tile<VEC, BD>(W + (size_t)d0 * FDIM + c, FDIM, lds, out + c, FDIM);
}

// down-proj with on-the-fly silu(g)*u staging; accumulates into x (residual)
__global__ __launch_bounds__(256) void gemv_down(
    const float* __restrict__ wd, const float* __restrict__ g, const float* __restrict__ u,
    float* __restrict__ x)
{
    constexpr int VEC = 2, BD = 256;
    __shared__ float lds[4 * BD];
    int d0 = blockIdx.y * BD;
    int cb = blockIdx.x * (64 * VEC);
    for (int i = threadIdx.x; i < 4 * BD; i += 256) {
        int ff = i >> 2, b = i & 3;
        float gv = g[(size_t)b * FDIM + d0 + ff];
        float uv = u[(size_t)b * FDIM + d0 + ff];
        lds[i] = gv / (1.f + expf(-gv)) * uv;
    }
    __syncthreads();
    gemv_tile<VEC, BD>(wd + (size_t)d0 * DMODEL + cb, DMODEL, lds, x + cb, DMODEL);
}

// ---------------- attention prep: q/k rmsnorm + rope, cache write ----------------
__device__ __forceinline__ void norm_rope_row(
    const float* __restrict__ row, const float* __restrict__ w, int pos,
    float* __restrict__ dst, int lane)
{
    float x1 = row[lane], x2 = row[lane + 64];
    float s = x1 * x1 + x2 * x2;
    #pragma unroll
    for (int off = 32; off; off >>= 1) s += __shfl_xor(s, off);
    float rr = rsqrtf(s * (1.f / 128.f) + EPSV);
    x1 *= rr * w[lane];
    x2 *= rr * w[lane + 64];
    // inv = THETA^(-lane/64) = exp(-lane * ln(1e6)/64)
    float inv = expf(-(float)lane * 0.21586735246819178f);
    float ang = (float)pos * inv;
    float cv = cosf(ang), sv = sinf(ang);
    dst[lane]      = x1 * cv - x2 * sv;
    dst[lane + 64] = x2 * cv + x1 * sv;
}

__global__ __launch_bounds__(64) void attn_prep(
    const float* __restrict__ qnw, const float* __restrict__ knw,
    float* __restrict__ qbuf, float* __restrict__ kbuf, const float* __restrict__ vbuf,
    float* __restrict__ kcache, float* __restrict__ vcache,  // pre-offset to layer
    const int* __restrict__ cpos)
{
    int r = blockIdx.x, lane = threadIdx.x;
    int pos = cpos[0];
    if (r < 64) {               // q rows: (b,h)
        int b = r >> 4, h = r & 15;
        float* row = qbuf + b * (NH * HDIM) + h * HDIM;
        norm_rope_row(row, qnw, pos, row, lane);
    } else if (r < 96) {        // k rows: (b,kv) -> cache
        int i = r - 64; int b = i >> 3, kv = i & 7;
        float* row = kbuf + b * (NKV * HDIM) + kv * HDIM;
        float* dst = kcache + ((size_t)(b * NKV + kv) * MAXP + pos) * HDIM;
        norm_rope_row(row, knw, pos, dst, lane);
    } else {                    // v rows: copy -> cache
        int i = r - 96; int b = i >> 3, kv = i & 7;
        const float* row = vbuf + b * (NKV * HDIM) + kv * HDIM;
        float* dst = vcache + ((size_t)(b * NKV + kv) * MAXP + pos) * HDIM;
        dst[lane] = row[lane];
        dst[lane + 64] = row[lane + 64];
    }
}

// ---------------- flash-decode attention ----------------
#define NSPLIT 16
#define CHUNK 256

__global__ __launch_bounds__(256) void attn_kernel(
    const float* __restrict__ qbuf,
    const float* __restrict__ kcache, const float* __restrict__ vcache,  // layer-offset
    const int* __restrict__ cpos,
    float2* __restrict__ part_ml, float* __restrict__ part_o)
{
    int bk = blockIdx.x;            // b*8+kv
    int split = blockIdx.y;
    int b = bk >> 3, kv = bk & 7;
    int T = cpos[0] + 1;
    int start = split * CHUNK;
    int n = min(CHUNK, T - start);
    int t = threadIdx.x, lane = t & 63, wave = t >> 6;
    if (n <= 0) {
        if (t < 2) part_ml[(bk * 2 + t) * NSPLIT + split] = make_float2(-1e30f, 0.f);
        return;
    }
    __shared__ float sc[2][CHUNK];
    const float* qb = qbuf + b * (NH * HDIM) + (kv * 2) * HDIM;
    float2 q0 = *(const float2*)(qb + 2 * lane);
    float2 q1 = *(const float2*)(qb + HDIM + 2 * lane);
    const float* kb = kcache + ((size_t)bk * MAXP + start) * HDIM;
    const float scale = 0.088388347648318447f;  // 1/sqrt(128)
    for (int p = wave; p < n; p += 4) {
        float2 kk = *(const float2*)(kb + (size_t)p * HDIM + 2 * lane);
        float d0 = kk.x * q0.x + kk.y * q0.y;
        float d1 = kk.x * q1.x + kk.y * q1.y;
        #pragma unroll
        for (int off = 32; off; off >>= 1) {
            d0 += __shfl_xor(d0, off);
            d1 += __shfl_xor(d1, off);
        }
        if (lane == 0) { sc[0][p] = d0 * scale; sc[1][p] = d1 * scale; }
    }
    __syncthreads();
    if (wave < 2) {
        float m = -1e30f;
        for (int p = lane; p < n; p += 64) m = fmaxf(m, sc[wave][p]);
        #pragma unroll
        for (int off = 32; off; off >>= 1) m = fmaxf(m, __shfl_xor(m, off));
        float l = 0.f;
        for (int p = lane; p < n; p += 64) {
            float e = expf(sc[wave][p] - m);
            sc[wave][p] = e;
            l += e;
        }
        #pragma unroll
        for (int off = 32; off; off >>= 1) l += __shfl_xor(l, off);
        if (lane == 0) part_ml[(bk * 2 + wave) * NSPLIT + split] = make_float2(m, l);
    }
    __syncthreads();
    int h2 = t >> 7, d = t & 127;
    const float* vb = vcache + ((size_t)bk * MAXP + start) * HDIM;
    float acc = 0.f;
    #pragma unroll 8
    for (int p = 0; p < n; ++p)
        acc = fmaf(sc[h2][p], vb[(size_t)p * HDIM + d], acc);
    part_o[((size_t)(bk * 2 + h2) * NSPLIT + split) * HDIM + d] = acc;
}

__global__ __launch_bounds__(128) void attn_reduce(
    const float2* __restrict__ part_ml, const float* __restrict__ part_o,
    float* __restrict__ obuf)
{
    int r = blockIdx.x;             // b*16+h
    int b = r >> 4, h = r & 15;
    int kv = h >> 1, h2 = h & 1;
    int base = ((b * 8 + kv) * 2 + h2) * NSPLIT;
    float2 ml[NSPLIT];
    float M = -1e30f;
    #pragma unroll
    for (int s = 0; s < NSPLIT; ++s) {
        ml[s] = part_ml[base + s];
        if (ml[s].y > 0.f) M = fmaxf(M, ml[s].x);
    }
    float L = 0.f;
    #pragma unroll
    for (int s = 0; s < NSPLIT; ++s)
        if (ml[s].y > 0.f) L += expf(ml[s].x - M) * ml[s].y;
    int d = threadIdx.x;
    float o = 0.f;
    #pragma unroll
    for (int s = 0; s < NSPLIT; ++s)
        if (ml[s].y > 0.f)
            o += expf(ml[s].x - M) * part_o[(size_t)(base + s) * HDIM + d];
    obuf[b * (NH * HDIM) + h * HDIM + d] = o / L;
}

// ---------------- launch ----------------
extern "C" void kernel_launch(void* const* d_in, const int* in_sizes, int n_in,
                              void* d_out, int out_size, void* d_ws, size_t ws_size,
                              hipStream_t stream)
{
    const int*   tok  = (const int*)d_in[0];
    const int*   cpos = (const int*)d_in[1];
    float* kcache = (float*)d_in[2];
    float* vcache = (float*)d_in[3];
    const float* embw = (const float*)d_in[4];
    const float* ln1w = (const float*)d_in[5];
    const float* wq   = (const float*)d_in[6];
    const float* wk   = (const float*)d_in[7];
    const float* wv   = (const float*)d_in[8];
    const float* qnw  = (const float*)d_in[9];
    const float* knw  = (const float*)d_in[10];
    const float* wo   = (const float*)d_in[11];
    const float* ln2w = (const float*)d_in[12];
    const float* wg   = (const float*)d_in[13];
    const float* wu   = (const float*)d_in[14];
    const float* wd   = (const float*)d_in[15];
    const float* fnw  = (const float*)d_in[16];
    const float* lmw  = (const float*)d_in[17];
    float* out = (float*)d_out;

    float* ws = (float*)d_ws;
    float* X   = ws;            // [4][2048]
    float* Hb  = X  + 8192;     // [4][2048]
    float* Qb  = Hb + 8192;     // [2][4][2048]
    float* Kb  = Qb + 16384;    // [2][4][1024]
    float* Vb  = Kb + 8192;     // [2][4][1024]
    float* Gb  = Vb + 8192;     // [2][4][8192]
    float* Ub  = Gb + 65536;    // [2][4][8192]
    float* Ob  = Ub + 65536;    // [4][2048]
    float* PML = Ob + 8192;     // [4*8*2*16] float2 = 2048 floats
    float* PO  = PML + 2048;    // [4*8*2*16][128] = 131072 floats

    // zero split-D accumulation buffers (Qb..Ub contiguous) and output
    hipMemsetAsync(Qb, 0, (size_t)(16384 + 8192 + 8192 + 65536 + 65536) * sizeof(float), stream);
    hipMemsetAsync(out, 0, (size_t)BATCH * VOCAB * sizeof(float), stream);

    embed_kernel<<<BATCH, 256, 0, stream>>>(embw, tok, X);

    for (int l = 0; l < LNUM; ++l) {
        float* q = Qb + l * 8192;
        float* k = Kb + l * 4096;
        float* v = Vb + l * 4096;
        float* g = Gb + l * 32768;
        float* u = Ub + l * 32768;
        float* kc = kcache + (size_t)l * BATCH * NKV * MAXP * HDIM;
        float* vc = vcache + (size_t)l * BATCH * NKV * MAXP * HDIM;

        rmsnorm_rows<<<BATCH, 256, 0, stream>>>(X, ln1w + l * DMODEL, Hb, DMODEL);
        gemv_qkv<<<dim3(32, 8), 256, 0, stream>>>(
            wq + (size_t)l * DMODEL * 2048, wk + (size_t)l * DMODEL * 1024,
            wv + (size_t)l * DMODEL * 1024, Hb, q, k, v);
        attn_prep<<<128, 64, 0, stream>>>(qnw + l * HDIM, knw + l * HDIM, q, k, v, kc, vc, cpos);
        attn_kernel<<<dim3(32, NSPLIT), 256, 0, stream>>>(q, kc, vc, cpos, (float2*)PML, PO);
        attn_reduce<<<64, 128, 0, stream>>>((const float2*)PML, PO, Ob);
        gemv_plain<2, 128><<<dim3(16, 16), 256, 0, stream>>>(
            wo + (size_t)l * 2048 * DMODEL, Ob, X, 2048, DMODEL);
        rmsnorm_rows<<<BATCH, 256, 0, stream>>>(X, ln2w + l * DMODEL, Hb, DMODEL);
        gemv_gateup<<<dim3(64, 8), 256, 0, stream>>>(
            wg + (size_t)l * DMODEL * FDIM, wu + (size_t)l * DMODEL * FDIM, Hb, g, u);
        gemv_down<<<dim3(16, 32), 256, 0, stream>>>(
            wd + (size_t)l * FDIM * DMODEL, g, u, X);
    }

    rmsnorm_rows<<<BATCH, 256, 0, stream>>>(X, fnw, Hb, DMODEL);
    gemv_plain<4, 256><<<dim3(125, 8), 256, 0, stream>>>(lmw, Hb, out, DMODEL, VOCAB);
}